// Round 1
// baseline (892.490 us; speedup 1.0000x reference)
//
#include <hip/hip_runtime.h>
#include <stdint.h>

#define NSAMP 1024
#define D 16384
#define WH 128
#define MARGIN 0.3f

typedef unsigned int uint;

__device__ __forceinline__ float bf2f(unsigned short b) {
    return __uint_as_float(((uint)b) << 16);
}
__device__ __forceinline__ unsigned short f2bf(float f) {
    uint u = __float_as_uint(f);
    u += 0x7fffu + ((u >> 16) & 1u);   // round-to-nearest-even (data has no NaN)
    return (unsigned short)(u >> 16);
}

// ---------------- kernel 1: row squared norms ----------------
__global__ void k_norms(const float* __restrict__ x, float* __restrict__ sq) {
    int b = blockIdx.x;
    int tid = threadIdx.x;
    const float4* xr = (const float4*)(x + (size_t)b * D);
    float s = 0.f;
    #pragma unroll
    for (int m = 0; m < 16; ++m) {
        float4 v = xr[tid + 256 * m];
        s += v.x * v.x + v.y * v.y + v.z * v.z + v.w * v.w;
    }
    for (int off = 32; off; off >>= 1) s += __shfl_down(s, off, 64);
    __shared__ float red[4];
    if ((tid & 63) == 0) red[tid >> 6] = s;
    __syncthreads();
    if (tid == 0) sq[b] = red[0] + red[1] + red[2] + red[3];
}

// ---------------- kernel 2: Gram partials, fp32 tiled GEMM ----------------
#define BK 16
__global__ __launch_bounds__(256) void k_gram(const float* __restrict__ x,
                                              float* __restrict__ Gp) {
    // grid: (bj=16, bi=16, ks=2); K split in halves, partial sums to Gp[ks]
    int bi = blockIdx.y, bj = blockIdx.x, ks = blockIdx.z;
    int i0 = bi * 64, j0 = bj * 64;
    int tid = threadIdx.x;
    int tx = tid & 15, ty = tid >> 4;
    int lrow = tid >> 2, lseg = tid & 3;

    __shared__ float As[BK][68];
    __shared__ float Bs[BK][68];

    const float* arow = x + (size_t)(i0 + lrow) * D + ks * (D / 2) + lseg * 4;
    const float* brow = x + (size_t)(j0 + lrow) * D + ks * (D / 2) + lseg * 4;

    float acc[4][4] = {};
    float4 pa = *(const float4*)arow;
    float4 pb = *(const float4*)brow;

    for (int kc = 0; kc < D / 2; kc += BK) {
        As[lseg * 4 + 0][lrow] = pa.x; As[lseg * 4 + 1][lrow] = pa.y;
        As[lseg * 4 + 2][lrow] = pa.z; As[lseg * 4 + 3][lrow] = pa.w;
        Bs[lseg * 4 + 0][lrow] = pb.x; Bs[lseg * 4 + 1][lrow] = pb.y;
        Bs[lseg * 4 + 2][lrow] = pb.z; Bs[lseg * 4 + 3][lrow] = pb.w;
        __syncthreads();
        if (kc + BK < D / 2) {
            pa = *(const float4*)(arow + kc + BK);
            pb = *(const float4*)(brow + kc + BK);
        }
        #pragma unroll
        for (int k = 0; k < BK; ++k) {
            float4 av = *(const float4*)&As[k][4 * ty];
            float4 bv = *(const float4*)&Bs[k][4 * tx];
            float a[4] = {av.x, av.y, av.z, av.w};
            float bb[4] = {bv.x, bv.y, bv.z, bv.w};
            #pragma unroll
            for (int ii = 0; ii < 4; ++ii)
                #pragma unroll
                for (int jj = 0; jj < 4; ++jj)
                    acc[ii][jj] += a[ii] * bb[jj];
        }
        __syncthreads();
    }
    float* Gbase = Gp + (size_t)ks * NSAMP * NSAMP;
    #pragma unroll
    for (int ii = 0; ii < 4; ++ii) {
        float4 v = {acc[ii][0], acc[ii][1], acc[ii][2], acc[ii][3]};
        *(float4*)&Gbase[(size_t)(i0 + 4 * ty + ii) * NSAMP + j0 + 4 * tx] = v;
    }
}

// ---------------- kernel 3: dist row -> hardest pos/neg indices ----------------
__global__ void k_select(const float* __restrict__ G0, const float* __restrict__ G1,
                         const float* __restrict__ sq, const int* __restrict__ tgt,
                         int* __restrict__ hp, int* __restrict__ hn,
                         float* __restrict__ dsq) {
    int i = blockIdx.x;
    int tid = threadIdx.x;
    float sqi = sq[i];
    int ti = tgt[i];
    float pv = -3.0e38f; int pj = 0x7FFFFFFF;
    float nv = 3.0e38f;  int nj = 0x7FFFFFFF;
    #pragma unroll
    for (int m = 0; m < 4; ++m) {
        int j = tid + 256 * m;
        float g = G0[(size_t)i * NSAMP + j] + G1[(size_t)i * NSAMP + j];
        float d2 = sqi + sq[j] - 2.f * g;
        float d = sqrtf(fmaxf(d2, 1e-12f));
        bool same = (tgt[j] == ti);
        float cp = same ? d : -1e30f;
        float cn = same ? 1e30f : d;
        if (cp > pv || (cp == pv && j < pj)) { pv = cp; pj = j; }
        if (cn < nv || (cn == nv && j < nj)) { nv = cn; nj = j; }
    }
    for (int off = 32; off; off >>= 1) {
        float opv = __shfl_down(pv, off, 64); int opj = __shfl_down(pj, off, 64);
        float onv = __shfl_down(nv, off, 64); int onj = __shfl_down(nj, off, 64);
        if (opv > pv || (opv == pv && opj < pj)) { pv = opv; pj = opj; }
        if (onv < nv || (onv == nv && onj < nj)) { nv = onv; nj = onj; }
    }
    __shared__ float spv[4], snv[4];
    __shared__ int spj[4], snj[4];
    if ((tid & 63) == 0) { int w = tid >> 6; spv[w] = pv; spj[w] = pj; snv[w] = nv; snj[w] = nj; }
    __syncthreads();
    if (tid == 0) {
        for (int w = 1; w < 4; ++w) {
            if (spv[w] > pv || (spv[w] == pv && spj[w] < pj)) { pv = spv[w]; pj = spj[w]; }
            if (snv[w] < nv || (snv[w] == nv && snj[w] < nj)) { nv = snv[w]; nj = snj[w]; }
        }
        hp[i] = pj; hn[i] = nj;
        dsq[i] = 0.f; dsq[NSAMP + i] = 0.f;   // zero accumulators for k_dc
    }
}

// ---------------- kernel 4: DC align + partial ||A - modi||^2 ----------------
// grid: (b=1024, which=2, q=4); block handles rows q*32..q*32+31 of anchor b
__global__ __launch_bounds__(256) void k_dc(const float* __restrict__ x,
                                            const int* __restrict__ hp,
                                            const int* __restrict__ hn,
                                            float* __restrict__ dsq) {
    int b = blockIdx.x;
    int which = blockIdx.y;
    int q = blockIdx.z;
    int oidx = (which == 0) ? hp[b] : hn[b];
    const float* Ag = x + (size_t)b * D + q * 32 * WH;
    const float* Og = x + (size_t)oidx * D;

    __shared__ __align__(16) unsigned short Abf[32][132];   // 8448 B
    __shared__ __align__(16) unsigned short Obf[128][132];  // 33792 B
    __shared__ __align__(16) float Pt[128][36];             // 18432 B (Pt[c][r] = exp-score)
    __shared__ float rowinv[32];
    __shared__ float red[4];

    int tid = threadIdx.x;
    #pragma unroll
    for (int m = 0; m < 4; ++m) {
        int v = tid + 256 * m;
        int r = v >> 5, c4 = v & 31;
        float4 f = *(const float4*)(Ag + r * WH + c4 * 4);
        ushort4 u; u.x = f2bf(f.x); u.y = f2bf(f.y); u.z = f2bf(f.z); u.w = f2bf(f.w);
        *(ushort4*)&Abf[r][c4 * 4] = u;
    }
    #pragma unroll
    for (int m = 0; m < 16; ++m) {
        int v = tid + 256 * m;
        int r = v >> 5, c4 = v & 31;
        float4 f = *(const float4*)(Og + r * WH + c4 * 4);
        ushort4 u; u.x = f2bf(f.x); u.y = f2bf(f.y); u.z = f2bf(f.z); u.w = f2bf(f.w);
        *(ushort4*)&Obf[r][c4 * 4] = u;
    }
    __syncthreads();

    int tx = tid & 31, ty = tid >> 5;
    // ---- S pass: S[r][c] = dot(A[r], O[c]) * scale ; rows r=4ty+ii, cols c=tx+32jj
    float acc[4][4] = {};
    for (int h0 = 0; h0 < WH; h0 += 4) {
        float a[4][4], o[4][4];
        #pragma unroll
        for (int ii = 0; ii < 4; ++ii) {
            ushort4 u = *(const ushort4*)&Abf[4 * ty + ii][h0];
            a[ii][0] = bf2f(u.x); a[ii][1] = bf2f(u.y); a[ii][2] = bf2f(u.z); a[ii][3] = bf2f(u.w);
        }
        #pragma unroll
        for (int jj = 0; jj < 4; ++jj) {
            ushort4 u = *(const ushort4*)&Obf[tx + 32 * jj][h0];
            o[jj][0] = bf2f(u.x); o[jj][1] = bf2f(u.y); o[jj][2] = bf2f(u.z); o[jj][3] = bf2f(u.w);
        }
        #pragma unroll
        for (int ii = 0; ii < 4; ++ii)
            #pragma unroll
            for (int jj = 0; jj < 4; ++jj)
                #pragma unroll
                for (int k = 0; k < 4; ++k)
                    acc[ii][jj] += a[ii][k] * o[jj][k];
    }
    const float scale = 0.08838834764831845f;  // 1/sqrt(128)
    #pragma unroll
    for (int jj = 0; jj < 4; ++jj) {
        int c = tx + 32 * jj;
        float4 v = {acc[0][jj] * scale, acc[1][jj] * scale,
                    acc[2][jj] * scale, acc[3][jj] * scale};
        *(float4*)&Pt[c][4 * ty] = v;
    }
    __syncthreads();

    // ---- row softmax over c (Pt stored transposed): 8 lanes per row
    {
        int r = tid >> 3, s = tid & 7;
        float vs[16];
        float mx = -3e38f;
        #pragma unroll
        for (int i2 = 0; i2 < 16; ++i2) { vs[i2] = Pt[s * 16 + i2][r]; mx = fmaxf(mx, vs[i2]); }
        #pragma unroll
        for (int off = 1; off < 8; off <<= 1) mx = fmaxf(mx, __shfl_xor(mx, off, 64));
        float sum = 0.f;
        #pragma unroll
        for (int i2 = 0; i2 < 16; ++i2) {
            float e = __expf(vs[i2] - mx);
            Pt[s * 16 + i2][r] = e;
            sum += e;
        }
        #pragma unroll
        for (int off = 1; off < 8; off <<= 1) sum += __shfl_xor(sum, off, 64);
        if (s == 0) rowinv[r] = 1.f / sum;
    }
    __syncthreads();

    // ---- M pass: M[r][h] = (sum_c Pt[c][r]*O[c][h]) * rowinv[r]; h=4tx+jj
    float macc[4][4] = {};
    for (int c = 0; c < 128; ++c) {
        float4 p = *(const float4*)&Pt[c][4 * ty];
        ushort4 u = *(const ushort4*)&Obf[c][4 * tx];
        float pp[4] = {p.x, p.y, p.z, p.w};
        float oo[4] = {bf2f(u.x), bf2f(u.y), bf2f(u.z), bf2f(u.w)};
        #pragma unroll
        for (int ii = 0; ii < 4; ++ii)
            #pragma unroll
            for (int jj = 0; jj < 4; ++jj)
                macc[ii][jj] += pp[ii] * oo[jj];
    }
    float local = 0.f;
    #pragma unroll
    for (int ii = 0; ii < 4; ++ii) {
        float inv = rowinv[4 * ty + ii];
        #pragma unroll
        for (int jj = 0; jj < 4; ++jj) {
            float Mv = macc[ii][jj] * inv;
            float Av = bf2f(Abf[4 * ty + ii][4 * tx + jj]);
            float dd = Av - Mv;
            local += dd * dd;
        }
    }
    for (int off = 32; off; off >>= 1) local += __shfl_down(local, off, 64);
    if ((tid & 63) == 0) red[tid >> 6] = local;
    __syncthreads();
    if (tid == 0) atomicAdd(&dsq[which * NSAMP + b], red[0] + red[1] + red[2] + red[3]);
}

// ---------------- kernel 5: final loss ----------------
__global__ void k_loss(const float* __restrict__ dsq, float* __restrict__ out) {
    int tid = threadIdx.x;
    float s = 0.f;
    #pragma unroll
    for (int m = 0; m < 4; ++m) {
        int b = tid + 256 * m;
        float ap = sqrtf(dsq[b]);
        float an = sqrtf(dsq[NSAMP + b]);
        s += fmaxf(ap - an + MARGIN, 0.f);
    }
    for (int off = 32; off; off >>= 1) s += __shfl_down(s, off, 64);
    __shared__ float red[4];
    if ((tid & 63) == 0) red[tid >> 6] = s;
    __syncthreads();
    if (tid == 0) out[0] = (red[0] + red[1] + red[2] + red[3]) * (1.f / NSAMP);
}

extern "C" void kernel_launch(void* const* d_in, const int* in_sizes, int n_in,
                              void* d_out, int out_size, void* d_ws, size_t ws_size,
                              hipStream_t stream) {
    const float* x = (const float*)d_in[0];
    const int* tgt = (const int*)d_in[1];
    float* out = (float*)d_out;
    char* ws = (char*)d_ws;

    float* G0 = (float*)ws;                                   // 4 MB (ks=0 partial)
    // ks=1 partial lives at G0 + NSAMP*NSAMP (contiguous)    // 4 MB
    float* G1 = G0 + (size_t)NSAMP * NSAMP;
    float* sq = (float*)(ws + (size_t)8 * 1024 * 1024);       // 4 KB
    float* dsq = sq + NSAMP;                                  // 8 KB (2*1024)
    int* hp = (int*)(dsq + 2 * NSAMP);                        // 4 KB
    int* hn = hp + NSAMP;                                     // 4 KB

    k_norms<<<NSAMP, 256, 0, stream>>>(x, sq);
    k_gram<<<dim3(16, 16, 2), 256, 0, stream>>>(x, G0);
    k_select<<<NSAMP, 256, 0, stream>>>(G0, G1, sq, tgt, hp, hn, dsq);
    k_dc<<<dim3(NSAMP, 2, 4), 256, 0, stream>>>(x, hp, hn, dsq);
    k_loss<<<1, 256, 0, stream>>>(dsq, out);
}

// Round 2
// 539.945 us; speedup vs baseline: 1.6529x; 1.6529x over previous
//
#include <hip/hip_runtime.h>
#include <stdint.h>

#define NSAMP 1024
#define D 16384
#define WH 128
#define MARGIN 0.3f
#define KS 8
#define KSUB (D / KS)

typedef unsigned int uint;
typedef unsigned short ushort_t;

typedef __attribute__((ext_vector_type(8))) short bf16x8;   // 8 bf16 = 4 VGPRs
typedef __attribute__((ext_vector_type(4))) float f32x4;

__device__ __forceinline__ float bf2f(unsigned short b) {
    return __uint_as_float(((uint)b) << 16);
}
__device__ __forceinline__ unsigned short f2bf(float f) {
    uint u = __float_as_uint(f);
    u += 0x7fffu + ((u >> 16) & 1u);   // RNE (data has no NaN)
    return (unsigned short)(u >> 16);
}
__device__ __forceinline__ void gload_lds16(const void* g, void* l) {
    __builtin_amdgcn_global_load_lds(
        (const __attribute__((address_space(1))) uint32_t*)g,
        (__attribute__((address_space(3))) uint32_t*)l, 16, 0, 0);
}

// ---------------- kernel 1: row norms + hi/lo bf16 split ----------------
__global__ __launch_bounds__(256) void k_norms_split(const float* __restrict__ x,
                                                     float* __restrict__ sq,
                                                     ushort_t* __restrict__ xhi,
                                                     ushort_t* __restrict__ xlo) {
    int b = blockIdx.x;
    int tid = threadIdx.x;
    const float* xr = x + (size_t)b * D;
    ushort_t* hr = xhi + (size_t)b * D;
    ushort_t* lr = xlo + (size_t)b * D;
    float s = 0.f;
    #pragma unroll
    for (int m = 0; m < 16; ++m) {
        int e = m * 1024 + tid * 4;
        float4 v = *(const float4*)(xr + e);
        s += v.x * v.x + v.y * v.y + v.z * v.z + v.w * v.w;
        ushort4 h, l;
        h.x = f2bf(v.x); l.x = f2bf(v.x - bf2f(h.x));
        h.y = f2bf(v.y); l.y = f2bf(v.y - bf2f(h.y));
        h.z = f2bf(v.z); l.z = f2bf(v.z - bf2f(h.z));
        h.w = f2bf(v.w); l.w = f2bf(v.w - bf2f(h.w));
        *(ushort4*)(hr + e) = h;
        *(ushort4*)(lr + e) = l;
    }
    for (int off = 32; off; off >>= 1) s += __shfl_down(s, off, 64);
    __shared__ float red[4];
    if ((tid & 63) == 0) red[tid >> 6] = s;
    __syncthreads();
    if (tid == 0) sq[b] = red[0] + red[1] + red[2] + red[3];
}

// ---------------- kernel 2: Gram via split-bf16 MFMA ----------------
// grid (bj=8, bi=8, ks=8); 128x128 tile per block, K-split partials into Gp[ks]
__global__ __launch_bounds__(256) void k_gram_mfma(const ushort_t* __restrict__ xhi,
                                                   const ushort_t* __restrict__ xlo,
                                                   float* __restrict__ Gp) {
    int bj = blockIdx.x, bi = blockIdx.y, ks = blockIdx.z;
    int i0 = bi * 128, j0 = bj * 128;
    int tid = threadIdx.x;
    int w = tid >> 6, lane = tid & 63;
    int wm = w & 1, wn = w >> 1;
    int quad = lane >> 4, m16 = lane & 15;
    int srow = lane >> 2, sseg = lane & 3;

    __shared__ __align__(16) ushort_t Ahi_s[128 * 32];
    __shared__ __align__(16) ushort_t Alo_s[128 * 32];
    __shared__ __align__(16) ushort_t Bhi_s[128 * 32];
    __shared__ __align__(16) ushort_t Blo_s[128 * 32];

    f32x4 acc[4][4];
    #pragma unroll
    for (int ii = 0; ii < 4; ++ii)
        #pragma unroll
        for (int jj = 0; jj < 4; ++jj)
            acc[ii][jj] = (f32x4){0.f, 0.f, 0.f, 0.f};

    const size_t Abase = (size_t)i0 * D;
    const size_t Bbase = (size_t)j0 * D;

    for (int kb = 0; kb < KSUB / 32; ++kb) {
        int k0 = ks * KSUB + kb * 32;
        // stage 128x32 of each matrix; wave w stages rows w*32..w*32+31
        #pragma unroll
        for (int c = 0; c < 2; ++c) {
            int r = w * 32 + c * 16 + srow;
            size_t go = (size_t)r * D + k0 + sseg * 8;
            int lo = (w * 32 + c * 16) * 32;   // element offset; lane lands at +lane*8
            gload_lds16(xhi + Abase + go, &Ahi_s[lo]);
            gload_lds16(xlo + Abase + go, &Alo_s[lo]);
            gload_lds16(xhi + Bbase + go, &Bhi_s[lo]);
            gload_lds16(xlo + Bbase + go, &Blo_s[lo]);
        }
        __syncthreads();

        bf16x8 ah[4], al[4], bh[4], bl[4];
        #pragma unroll
        for (int ii = 0; ii < 4; ++ii) {
            int ar = wm * 64 + ii * 16 + m16;
            ah[ii] = *(const bf16x8*)&Ahi_s[ar * 32 + quad * 8];
            al[ii] = *(const bf16x8*)&Alo_s[ar * 32 + quad * 8];
        }
        #pragma unroll
        for (int jj = 0; jj < 4; ++jj) {
            int br = wn * 64 + jj * 16 + m16;
            bh[jj] = *(const bf16x8*)&Bhi_s[br * 32 + quad * 8];
            bl[jj] = *(const bf16x8*)&Blo_s[br * 32 + quad * 8];
        }
        #pragma unroll
        for (int ii = 0; ii < 4; ++ii)
            #pragma unroll
            for (int jj = 0; jj < 4; ++jj) {
                acc[ii][jj] = __builtin_amdgcn_mfma_f32_16x16x32_bf16(ah[ii], bh[jj], acc[ii][jj], 0, 0, 0);
                acc[ii][jj] = __builtin_amdgcn_mfma_f32_16x16x32_bf16(ah[ii], bl[jj], acc[ii][jj], 0, 0, 0);
                acc[ii][jj] = __builtin_amdgcn_mfma_f32_16x16x32_bf16(al[ii], bh[jj], acc[ii][jj], 0, 0, 0);
            }
        __syncthreads();
    }

    float* Gb = Gp + (size_t)ks * NSAMP * NSAMP;
    #pragma unroll
    for (int ii = 0; ii < 4; ++ii)
        #pragma unroll
        for (int jj = 0; jj < 4; ++jj) {
            int rg = i0 + wm * 64 + ii * 16 + quad * 4;
            int cg = j0 + wn * 64 + jj * 16 + m16;
            #pragma unroll
            for (int r = 0; r < 4; ++r)
                Gb[(size_t)(rg + r) * NSAMP + cg] = acc[ii][jj][r];
        }
}

// ---------------- kernel 3: dist row -> hardest pos/neg indices ----------------
__global__ void k_select(const float* __restrict__ Gp,
                         const float* __restrict__ sq, const int* __restrict__ tgt,
                         int* __restrict__ hp, int* __restrict__ hn,
                         float* __restrict__ dsq) {
    int i = blockIdx.x;
    int tid = threadIdx.x;
    float sqi = sq[i];
    int ti = tgt[i];
    float pv = -3.0e38f; int pj = 0x7FFFFFFF;
    float nv = 3.0e38f;  int nj = 0x7FFFFFFF;
    #pragma unroll
    for (int m = 0; m < 4; ++m) {
        int j = tid + 256 * m;
        float g = 0.f;
        #pragma unroll
        for (int s = 0; s < KS; ++s)
            g += Gp[(size_t)s * NSAMP * NSAMP + (size_t)i * NSAMP + j];
        float d2 = sqi + sq[j] - 2.f * g;
        float d = sqrtf(fmaxf(d2, 1e-12f));
        bool same = (tgt[j] == ti);
        float cp = same ? d : -1e30f;
        float cn = same ? 1e30f : d;
        if (cp > pv || (cp == pv && j < pj)) { pv = cp; pj = j; }
        if (cn < nv || (cn == nv && j < nj)) { nv = cn; nj = j; }
    }
    for (int off = 32; off; off >>= 1) {
        float opv = __shfl_down(pv, off, 64); int opj = __shfl_down(pj, off, 64);
        float onv = __shfl_down(nv, off, 64); int onj = __shfl_down(nj, off, 64);
        if (opv > pv || (opv == pv && opj < pj)) { pv = opv; pj = opj; }
        if (onv < nv || (onv == nv && onj < nj)) { nv = onv; nj = onj; }
    }
    __shared__ float spv[4], snv[4];
    __shared__ int spj[4], snj[4];
    if ((tid & 63) == 0) { int wv = tid >> 6; spv[wv] = pv; spj[wv] = pj; snv[wv] = nv; snj[wv] = nj; }
    __syncthreads();
    if (tid == 0) {
        for (int wv = 1; wv < 4; ++wv) {
            if (spv[wv] > pv || (spv[wv] == pv && spj[wv] < pj)) { pv = spv[wv]; pj = spj[wv]; }
            if (snv[wv] < nv || (snv[wv] == nv && snj[wv] < nj)) { nv = snv[wv]; nj = snj[wv]; }
        }
        hp[i] = pj; hn[i] = nj;
        dsq[i] = 0.f; dsq[NSAMP + i] = 0.f;   // zero accumulators for k_dc
    }
}

// ---------------- kernel 4: DC align + partial ||A - modi||^2 ----------------
// grid: (b=1024, which=2, q=4); block handles rows q*32..q*32+31 of anchor b
__global__ __launch_bounds__(256) void k_dc(const float* __restrict__ x,
                                            const int* __restrict__ hp,
                                            const int* __restrict__ hn,
                                            float* __restrict__ dsq) {
    int b = blockIdx.x;
    int which = blockIdx.y;
    int q = blockIdx.z;
    int oidx = (which == 0) ? hp[b] : hn[b];
    const float* Ag = x + (size_t)b * D + q * 32 * WH;
    const float* Og = x + (size_t)oidx * D;

    __shared__ __align__(16) unsigned short Abf[32][132];   // 8448 B
    __shared__ __align__(16) unsigned short Obf[128][132];  // 33792 B
    __shared__ __align__(16) float Pt[128][36];             // 18432 B (Pt[c][r] = exp-score)
    __shared__ float rowinv[32];
    __shared__ float red[4];

    int tid = threadIdx.x;
    #pragma unroll
    for (int m = 0; m < 4; ++m) {
        int v = tid + 256 * m;
        int r = v >> 5, c4 = v & 31;
        float4 f = *(const float4*)(Ag + r * WH + c4 * 4);
        ushort4 u; u.x = f2bf(f.x); u.y = f2bf(f.y); u.z = f2bf(f.z); u.w = f2bf(f.w);
        *(ushort4*)&Abf[r][c4 * 4] = u;
    }
    #pragma unroll
    for (int m = 0; m < 16; ++m) {
        int v = tid + 256 * m;
        int r = v >> 5, c4 = v & 31;
        float4 f = *(const float4*)(Og + r * WH + c4 * 4);
        ushort4 u; u.x = f2bf(f.x); u.y = f2bf(f.y); u.z = f2bf(f.z); u.w = f2bf(f.w);
        *(ushort4*)&Obf[r][c4 * 4] = u;
    }
    __syncthreads();

    int tx = tid & 31, ty = tid >> 5;
    // ---- S pass: S[r][c] = dot(A[r], O[c]) * scale ; rows r=4ty+ii, cols c=tx+32jj
    float acc[4][4] = {};
    for (int h0 = 0; h0 < WH; h0 += 4) {
        float a[4][4], o[4][4];
        #pragma unroll
        for (int ii = 0; ii < 4; ++ii) {
            ushort4 u = *(const ushort4*)&Abf[4 * ty + ii][h0];
            a[ii][0] = bf2f(u.x); a[ii][1] = bf2f(u.y); a[ii][2] = bf2f(u.z); a[ii][3] = bf2f(u.w);
        }
        #pragma unroll
        for (int jj = 0; jj < 4; ++jj) {
            ushort4 u = *(const ushort4*)&Obf[tx + 32 * jj][h0];
            o[jj][0] = bf2f(u.x); o[jj][1] = bf2f(u.y); o[jj][2] = bf2f(u.z); o[jj][3] = bf2f(u.w);
        }
        #pragma unroll
        for (int ii = 0; ii < 4; ++ii)
            #pragma unroll
            for (int jj = 0; jj < 4; ++jj)
                #pragma unroll
                for (int k = 0; k < 4; ++k)
                    acc[ii][jj] += a[ii][k] * o[jj][k];
    }
    const float scale = 0.08838834764831845f;  // 1/sqrt(128)
    #pragma unroll
    for (int jj = 0; jj < 4; ++jj) {
        int c = tx + 32 * jj;
        float4 v = {acc[0][jj] * scale, acc[1][jj] * scale,
                    acc[2][jj] * scale, acc[3][jj] * scale};
        *(float4*)&Pt[c][4 * ty] = v;
    }
    __syncthreads();

    // ---- row softmax over c (Pt stored transposed): 8 lanes per row
    {
        int r = tid >> 3, s = tid & 7;
        float vs[16];
        float mx = -3e38f;
        #pragma unroll
        for (int i2 = 0; i2 < 16; ++i2) { vs[i2] = Pt[s * 16 + i2][r]; mx = fmaxf(mx, vs[i2]); }
        #pragma unroll
        for (int off = 1; off < 8; off <<= 1) mx = fmaxf(mx, __shfl_xor(mx, off, 64));
        float sum = 0.f;
        #pragma unroll
        for (int i2 = 0; i2 < 16; ++i2) {
            float e = __expf(vs[i2] - mx);
            Pt[s * 16 + i2][r] = e;
            sum += e;
        }
        #pragma unroll
        for (int off = 1; off < 8; off <<= 1) sum += __shfl_xor(sum, off, 64);
        if (s == 0) rowinv[r] = 1.f / sum;
    }
    __syncthreads();

    // ---- M pass: M[r][h] = (sum_c Pt[c][r]*O[c][h]) * rowinv[r]; h=4tx+jj
    float macc[4][4] = {};
    for (int c = 0; c < 128; ++c) {
        float4 p = *(const float4*)&Pt[c][4 * ty];
        ushort4 u = *(const ushort4*)&Obf[c][4 * tx];
        float pp[4] = {p.x, p.y, p.z, p.w};
        float oo[4] = {bf2f(u.x), bf2f(u.y), bf2f(u.z), bf2f(u.w)};
        #pragma unroll
        for (int ii = 0; ii < 4; ++ii)
            #pragma unroll
            for (int jj = 0; jj < 4; ++jj)
                macc[ii][jj] += pp[ii] * oo[jj];
    }
    float local = 0.f;
    #pragma unroll
    for (int ii = 0; ii < 4; ++ii) {
        float inv = rowinv[4 * ty + ii];
        #pragma unroll
        for (int jj = 0; jj < 4; ++jj) {
            float Mv = macc[ii][jj] * inv;
            float Av = bf2f(Abf[4 * ty + ii][4 * tx + jj]);
            float dd = Av - Mv;
            local += dd * dd;
        }
    }
    for (int off = 32; off; off >>= 1) local += __shfl_down(local, off, 64);
    if ((tid & 63) == 0) red[tid >> 6] = local;
    __syncthreads();
    if (tid == 0) atomicAdd(&dsq[which * NSAMP + b], red[0] + red[1] + red[2] + red[3]);
}

// ---------------- kernel 5: final loss ----------------
__global__ void k_loss(const float* __restrict__ dsq, float* __restrict__ out) {
    int tid = threadIdx.x;
    float s = 0.f;
    #pragma unroll
    for (int m = 0; m < 4; ++m) {
        int b = tid + 256 * m;
        float ap = sqrtf(dsq[b]);
        float an = sqrtf(dsq[NSAMP + b]);
        s += fmaxf(ap - an + MARGIN, 0.f);
    }
    for (int off = 32; off; off >>= 1) s += __shfl_down(s, off, 64);
    __shared__ float red[4];
    if ((tid & 63) == 0) red[tid >> 6] = s;
    __syncthreads();
    if (tid == 0) out[0] = (red[0] + red[1] + red[2] + red[3]) * (1.f / NSAMP);
}

extern "C" void kernel_launch(void* const* d_in, const int* in_sizes, int n_in,
                              void* d_out, int out_size, void* d_ws, size_t ws_size,
                              hipStream_t stream) {
    const float* x = (const float*)d_in[0];
    const int* tgt = (const int*)d_in[1];
    float* out = (float*)d_out;
    char* ws = (char*)d_ws;

    float* Gp = (float*)ws;                                       // KS * 4 MB = 32 MB
    ushort_t* xhi = (ushort_t*)(ws + (size_t)32 * 1024 * 1024);   // 32 MB
    ushort_t* xlo = xhi + (size_t)NSAMP * D;                      // 32 MB
    float* sq = (float*)(ws + (size_t)96 * 1024 * 1024);          // 4 KB
    float* dsq = sq + NSAMP;                                      // 8 KB
    int* hp = (int*)(dsq + 2 * NSAMP);                            // 4 KB
    int* hn = hp + NSAMP;                                         // 4 KB

    k_norms_split<<<NSAMP, 256, 0, stream>>>(x, sq, xhi, xlo);
    k_gram_mfma<<<dim3(8, 8, KS), 256, 0, stream>>>(xhi, xlo, Gp);
    k_select<<<NSAMP, 256, 0, stream>>>(Gp, sq, tgt, hp, hn, dsq);
    k_dc<<<dim3(NSAMP, 2, 4), 256, 0, stream>>>(x, hp, hn, dsq);
    k_loss<<<1, 256, 0, stream>>>(dsq, out);
}

// Round 3
// 267.678 us; speedup vs baseline: 3.3342x; 2.0171x over previous
//
#include <hip/hip_runtime.h>
#include <stdint.h>

#define NSAMP 1024
#define D 16384
#define WH 128
#define MARGIN 0.3f
#define KS 8
#define KSUB (D / KS)
#define SCALE 0.08838834764831845f    // 1/sqrt(128)
#define RSCALE 11.313708498984761f    // sqrt(128)

typedef unsigned int uint;
typedef unsigned short ushort_t;

typedef __attribute__((ext_vector_type(8))) short bf16x8;   // 8 bf16 = 4 VGPRs
typedef __attribute__((ext_vector_type(4))) float f32x4;

__device__ __forceinline__ float bf2f(unsigned short b) {
    return __uint_as_float(((uint)b) << 16);
}
__device__ __forceinline__ unsigned short f2bf(float f) {
    uint u = __float_as_uint(f);
    u += 0x7fffu + ((u >> 16) & 1u);   // RNE (data has no NaN)
    return (unsigned short)(u >> 16);
}
__device__ __forceinline__ void gload_lds16(const void* g, void* l) {
    __builtin_amdgcn_global_load_lds(
        (const __attribute__((address_space(1))) uint32_t*)g,
        (__attribute__((address_space(3))) uint32_t*)l, 16, 0, 0);
}
// Swizzled LDS byte offset for a 128-col bf16 row-major tile:
// 16B chunks XOR'd with row&15 -> MFMA frag reads hit banks uniformly.
__device__ __forceinline__ int lds_off(int row, int col) {
    return row * 256 + ((((col >> 3) ^ (row & 15)) << 4) | ((col & 7) << 1));
}

// ---------------- kernel 1: row norms + hi/lo bf16 split ----------------
__global__ __launch_bounds__(256) void k_norms_split(const float* __restrict__ x,
                                                     float* __restrict__ sq,
                                                     ushort_t* __restrict__ xhi,
                                                     ushort_t* __restrict__ xlo) {
    int b = blockIdx.x;
    int tid = threadIdx.x;
    const float* xr = x + (size_t)b * D;
    ushort_t* hr = xhi + (size_t)b * D;
    ushort_t* lr = xlo + (size_t)b * D;
    float s = 0.f;
    #pragma unroll
    for (int m = 0; m < 16; ++m) {
        int e = m * 1024 + tid * 4;
        float4 v = *(const float4*)(xr + e);
        s += v.x * v.x + v.y * v.y + v.z * v.z + v.w * v.w;
        ushort4 h, l;
        h.x = f2bf(v.x); l.x = f2bf(v.x - bf2f(h.x));
        h.y = f2bf(v.y); l.y = f2bf(v.y - bf2f(h.y));
        h.z = f2bf(v.z); l.z = f2bf(v.z - bf2f(h.z));
        h.w = f2bf(v.w); l.w = f2bf(v.w - bf2f(h.w));
        *(ushort4*)(hr + e) = h;
        *(ushort4*)(lr + e) = l;
    }
    for (int off = 32; off; off >>= 1) s += __shfl_down(s, off, 64);
    __shared__ float red[4];
    if ((tid & 63) == 0) red[tid >> 6] = s;
    __syncthreads();
    if (tid == 0) sq[b] = red[0] + red[1] + red[2] + red[3];
}

// ---------------- kernel 2: Gram via split-bf16 MFMA ----------------
__global__ __launch_bounds__(256) void k_gram_mfma(const ushort_t* __restrict__ xhi,
                                                   const ushort_t* __restrict__ xlo,
                                                   float* __restrict__ Gp) {
    int bj = blockIdx.x, bi = blockIdx.y, ks = blockIdx.z;
    int i0 = bi * 128, j0 = bj * 128;
    int tid = threadIdx.x;
    int w = tid >> 6, lane = tid & 63;
    int wm = w & 1, wn = w >> 1;
    int quad = lane >> 4, m16 = lane & 15;
    int srow = lane >> 2, sseg = lane & 3;

    __shared__ __align__(16) ushort_t Ahi_s[128 * 32];
    __shared__ __align__(16) ushort_t Alo_s[128 * 32];
    __shared__ __align__(16) ushort_t Bhi_s[128 * 32];
    __shared__ __align__(16) ushort_t Blo_s[128 * 32];

    f32x4 acc[4][4];
    #pragma unroll
    for (int ii = 0; ii < 4; ++ii)
        #pragma unroll
        for (int jj = 0; jj < 4; ++jj)
            acc[ii][jj] = (f32x4){0.f, 0.f, 0.f, 0.f};

    const size_t Abase = (size_t)i0 * D;
    const size_t Bbase = (size_t)j0 * D;

    for (int kb = 0; kb < KSUB / 32; ++kb) {
        int k0 = ks * KSUB + kb * 32;
        #pragma unroll
        for (int c = 0; c < 2; ++c) {
            int r = w * 32 + c * 16 + srow;
            size_t go = (size_t)r * D + k0 + sseg * 8;
            int lo = (w * 32 + c * 16) * 32;
            gload_lds16(xhi + Abase + go, &Ahi_s[lo]);
            gload_lds16(xlo + Abase + go, &Alo_s[lo]);
            gload_lds16(xhi + Bbase + go, &Bhi_s[lo]);
            gload_lds16(xlo + Bbase + go, &Blo_s[lo]);
        }
        __syncthreads();

        bf16x8 ah[4], al[4], bh[4], bl[4];
        #pragma unroll
        for (int ii = 0; ii < 4; ++ii) {
            int ar = wm * 64 + ii * 16 + m16;
            ah[ii] = *(const bf16x8*)&Ahi_s[ar * 32 + quad * 8];
            al[ii] = *(const bf16x8*)&Alo_s[ar * 32 + quad * 8];
        }
        #pragma unroll
        for (int jj = 0; jj < 4; ++jj) {
            int br = wn * 64 + jj * 16 + m16;
            bh[jj] = *(const bf16x8*)&Bhi_s[br * 32 + quad * 8];
            bl[jj] = *(const bf16x8*)&Blo_s[br * 32 + quad * 8];
        }
        #pragma unroll
        for (int ii = 0; ii < 4; ++ii)
            #pragma unroll
            for (int jj = 0; jj < 4; ++jj) {
                acc[ii][jj] = __builtin_amdgcn_mfma_f32_16x16x32_bf16(ah[ii], bh[jj], acc[ii][jj], 0, 0, 0);
                acc[ii][jj] = __builtin_amdgcn_mfma_f32_16x16x32_bf16(ah[ii], bl[jj], acc[ii][jj], 0, 0, 0);
                acc[ii][jj] = __builtin_amdgcn_mfma_f32_16x16x32_bf16(al[ii], bh[jj], acc[ii][jj], 0, 0, 0);
            }
        __syncthreads();
    }

    float* Gb = Gp + (size_t)ks * NSAMP * NSAMP;
    #pragma unroll
    for (int ii = 0; ii < 4; ++ii)
        #pragma unroll
        for (int jj = 0; jj < 4; ++jj) {
            int rg = i0 + wm * 64 + ii * 16 + quad * 4;
            int cg = j0 + wn * 64 + jj * 16 + m16;
            #pragma unroll
            for (int r = 0; r < 4; ++r)
                Gb[(size_t)(rg + r) * NSAMP + cg] = acc[ii][jj][r];
        }
}

// ---------------- kernel 3: dist row -> hardest pos/neg + dsq init ----------------
__global__ void k_select(const float* __restrict__ Gp,
                         const float* __restrict__ sq, const int* __restrict__ tgt,
                         int* __restrict__ hp, int* __restrict__ hn,
                         float* __restrict__ dsq) {
    int i = blockIdx.x;
    int tid = threadIdx.x;
    float sqi = sq[i];
    int ti = tgt[i];
    float pv = -3.0e38f; int pj = 0x7FFFFFFF;
    float nv = 3.0e38f;  int nj = 0x7FFFFFFF;
    #pragma unroll
    for (int m = 0; m < 4; ++m) {
        int j = tid + 256 * m;
        float g = 0.f;
        #pragma unroll
        for (int s = 0; s < KS; ++s)
            g += Gp[(size_t)s * NSAMP * NSAMP + (size_t)i * NSAMP + j];
        float d2 = sqi + sq[j] - 2.f * g;
        float d = sqrtf(fmaxf(d2, 1e-12f));
        bool same = (tgt[j] == ti);
        float cp = same ? d : -1e30f;
        float cn = same ? 1e30f : d;
        if (cp > pv || (cp == pv && j < pj)) { pv = cp; pj = j; }
        if (cn < nv || (cn == nv && j < nj)) { nv = cn; nj = j; }
    }
    for (int off = 32; off; off >>= 1) {
        float opv = __shfl_down(pv, off, 64); int opj = __shfl_down(pj, off, 64);
        float onv = __shfl_down(nv, off, 64); int onj = __shfl_down(nj, off, 64);
        if (opv > pv || (opv == pv && opj < pj)) { pv = opv; pj = opj; }
        if (onv < nv || (onv == nv && onj < nj)) { nv = onv; nj = onj; }
    }
    __shared__ float spv[4], snv[4];
    __shared__ int spj[4], snj[4];
    if ((tid & 63) == 0) { int wv = tid >> 6; spv[wv] = pv; spj[wv] = pj; snv[wv] = nv; snj[wv] = nj; }
    __syncthreads();
    if (tid == 0) {
        for (int wv = 1; wv < 4; ++wv) {
            if (spv[wv] > pv || (spv[wv] == pv && spj[wv] < pj)) { pv = spv[wv]; pj = spj[wv]; }
            if (snv[wv] < nv || (snv[wv] == nv && snj[wv] < nj)) { nv = snv[wv]; nj = snj[wv]; }
        }
        hp[i] = pj; hn[i] = nj;
        // dsq = ||A||^2 init; k_dc adds (-2*Tr(A.M) + ||M||^2)
        dsq[i] = sqi; dsq[NSAMP + i] = sqi;
    }
}

// ---------------- kernel 4: DC align via MFMA (flash-style) ----------------
// grid (b=1024, which=2), block 256 = 4 waves. Per block:
//   S^T = MFMA(O, A) -> softmax over c (in-lane) -> P(normalized bf16) to LDS
//   in-place transpose O->Ot -> M = MFMA(P, Ot)
//   dsq += -2*sum(S0*P) + sum(M^2)     (||A||^2 pre-added in k_select)
__global__ __launch_bounds__(256) void k_dc_mfma(const ushort_t* __restrict__ xhi,
                                                 const int* __restrict__ hp,
                                                 const int* __restrict__ hn,
                                                 float* __restrict__ dsq) {
    int b = blockIdx.x;
    int which = blockIdx.y;
    int oidx = (which == 0) ? hp[b] : hn[b];
    const ushort_t* Ag = xhi + (size_t)b * D;
    const ushort_t* Og = xhi + (size_t)oidx * D;

    __shared__ __align__(16) char smem[65536];   // [0,32K): O then Ot; [32K,64K): P

    int tid = threadIdx.x;
    int wv = tid >> 6, lane = tid & 63;
    int quad = lane >> 4, m16 = lane & 15;

    // A-frags straight from global (B-operand of S^T pass): rows r, k-chunks of h
    bf16x8 af[2][4];
    #pragma unroll
    for (int tj2 = 0; tj2 < 2; ++tj2) {
        int r = (2 * wv + tj2) * 16 + m16;
        #pragma unroll
        for (int ks = 0; ks < 4; ++ks)
            af[tj2][ks] = *(const bf16x8*)(Ag + r * WH + ks * 32 + quad * 8);
    }

    // stage O into swizzled LDS
    uint4 stg[8];
    #pragma unroll
    for (int k = 0; k < 8; ++k)
        stg[k] = *(const uint4*)((const char*)Og + (size_t)(tid + 256 * k) * 16);
    #pragma unroll
    for (int k = 0; k < 8; ++k) {
        int g = tid + 256 * k;
        *(uint4*)(smem + lds_off(g >> 4, (g & 15) * 8)) = stg[k];
    }
    __syncthreads();

    // ---- S^T pass: tile (ti: c-rows, tj2: r-cols 2wv+tj2) ----
    f32x4 accS[8][2];
    #pragma unroll
    for (int ti = 0; ti < 8; ++ti)
        #pragma unroll
        for (int tj2 = 0; tj2 < 2; ++tj2)
            accS[ti][tj2] = (f32x4){0.f, 0.f, 0.f, 0.f};
    #pragma unroll
    for (int ks = 0; ks < 4; ++ks) {
        bf16x8 of[8];
        #pragma unroll
        for (int ti = 0; ti < 8; ++ti)
            of[ti] = *(const bf16x8*)(smem + lds_off(ti * 16 + m16, (ks * 4 + quad) * 8));
        #pragma unroll
        for (int ti = 0; ti < 8; ++ti)
            #pragma unroll
            for (int tj2 = 0; tj2 < 2; ++tj2)
                accS[ti][tj2] = __builtin_amdgcn_mfma_f32_16x16x32_bf16(of[ti], af[tj2][ks], accS[ti][tj2], 0, 0, 0);
    }

    // ---- transpose read phase (still original O in LDS) ----
    int c0 = (tid & 31) * 4, h0 = (tid >> 5) * 16;
    uint4 trd[4][2];
    #pragma unroll
    for (int j = 0; j < 4; ++j)
        #pragma unroll
        for (int k = 0; k < 2; ++k)
            trd[j][k] = *(const uint4*)(smem + lds_off(c0 + j, h0 + 8 * k));

    // ---- softmax over c (regs + quad shuffles), write normalized bf16 P, T partial ----
    float tpart = 0.f;
    #pragma unroll
    for (int tj2 = 0; tj2 < 2; ++tj2) {
        float mx = -3.0e38f;
        #pragma unroll
        for (int ti = 0; ti < 8; ++ti)
            #pragma unroll
            for (int r = 0; r < 4; ++r) {
                float s = accS[ti][tj2][r] * SCALE;
                accS[ti][tj2][r] = s;
                mx = fmaxf(mx, s);
            }
        mx = fmaxf(mx, __shfl_xor(mx, 16, 64));
        mx = fmaxf(mx, __shfl_xor(mx, 32, 64));
        float sum = 0.f;
        #pragma unroll
        for (int ti = 0; ti < 8; ++ti)
            #pragma unroll
            for (int r = 0; r < 4; ++r)
                sum += __expf(accS[ti][tj2][r] - mx);
        sum += __shfl_xor(sum, 16, 64);
        sum += __shfl_xor(sum, 32, 64);
        float inv = 1.f / sum;
        int rrow = (2 * wv + tj2) * 16 + m16;
        #pragma unroll
        for (int ti = 0; ti < 8; ++ti) {
            uint pk0 = 0, pk1 = 0;
            #pragma unroll
            for (int r = 0; r < 4; ++r) {
                float s = accS[ti][tj2][r];
                float p = __expf(s - mx) * inv;
                unsigned short pb = f2bf(p);
                tpart += s * bf2f(pb);     // T' = sum(s_scaled * P); T = T'*RSCALE
                uint pu = (uint)pb << ((r & 1) * 16);
                if (r < 2) pk0 |= pu; else pk1 |= pu;
            }
            *(uint2*)(smem + 32768 + lds_off(rrow, ti * 16 + quad * 4)) = make_uint2(pk0, pk1);
        }
    }
    __syncthreads();   // everyone done reading O

    // ---- transpose write phase: (c,h) -> (h,c) in place ----
    #pragma unroll
    for (int i = 0; i < 16; ++i) {
        uint v[4];
        #pragma unroll
        for (int j = 0; j < 4; ++j) {
            uint wo = ((const uint*)&trd[j][i >> 3])[(i >> 1) & 3];
            v[j] = (i & 1) ? (wo >> 16) : (wo & 0xffffu);
        }
        uint2 pk;
        pk.x = v[0] | (v[1] << 16);
        pk.y = v[2] | (v[3] << 16);
        *(uint2*)(smem + lds_off(h0 + i, c0)) = pk;
    }
    __syncthreads();   // Ot + P ready

    // ---- M pass: M = P . O  via MFMA(P-frags, Ot-frags) ----
    f32x4 accM[2][8];
    #pragma unroll
    for (int tj2 = 0; tj2 < 2; ++tj2)
        #pragma unroll
        for (int tj = 0; tj < 8; ++tj)
            accM[tj2][tj] = (f32x4){0.f, 0.f, 0.f, 0.f};
    #pragma unroll
    for (int ks = 0; ks < 4; ++ks) {
        bf16x8 pfr[2], otf[8];
        #pragma unroll
        for (int tj2 = 0; tj2 < 2; ++tj2)
            pfr[tj2] = *(const bf16x8*)(smem + 32768 + lds_off((2 * wv + tj2) * 16 + m16, (ks * 4 + quad) * 8));
        #pragma unroll
        for (int tj = 0; tj < 8; ++tj)
            otf[tj] = *(const bf16x8*)(smem + lds_off(tj * 16 + m16, (ks * 4 + quad) * 8));
        #pragma unroll
        for (int tj2 = 0; tj2 < 2; ++tj2)
            #pragma unroll
            for (int tj = 0; tj < 8; ++tj)
                accM[tj2][tj] = __builtin_amdgcn_mfma_f32_16x16x32_bf16(pfr[tj2], otf[tj], accM[tj2][tj], 0, 0, 0);
    }

    float m2 = 0.f;
    #pragma unroll
    for (int tj2 = 0; tj2 < 2; ++tj2)
        #pragma unroll
        for (int tj = 0; tj < 8; ++tj)
            #pragma unroll
            for (int r = 0; r < 4; ++r) {
                float mvv = accM[tj2][tj][r];
                m2 += mvv * mvv;
            }
    float part = m2 - 2.f * RSCALE * tpart;
    for (int off = 32; off; off >>= 1) part += __shfl_down(part, off, 64);
    if (lane == 0) atomicAdd(&dsq[which * NSAMP + b], part);
}

// ---------------- kernel 5: final loss ----------------
__global__ void k_loss(const float* __restrict__ dsq, float* __restrict__ out) {
    int tid = threadIdx.x;
    float s = 0.f;
    #pragma unroll
    for (int m = 0; m < 4; ++m) {
        int b = tid + 256 * m;
        float ap = sqrtf(fmaxf(dsq[b], 0.f));
        float an = sqrtf(fmaxf(dsq[NSAMP + b], 0.f));
        s += fmaxf(ap - an + MARGIN, 0.f);
    }
    for (int off = 32; off; off >>= 1) s += __shfl_down(s, off, 64);
    __shared__ float red[4];
    if ((tid & 63) == 0) red[tid >> 6] = s;
    __syncthreads();
    if (tid == 0) out[0] = (red[0] + red[1] + red[2] + red[3]) * (1.f / NSAMP);
}

extern "C" void kernel_launch(void* const* d_in, const int* in_sizes, int n_in,
                              void* d_out, int out_size, void* d_ws, size_t ws_size,
                              hipStream_t stream) {
    const float* x = (const float*)d_in[0];
    const int* tgt = (const int*)d_in[1];
    float* out = (float*)d_out;
    char* ws = (char*)d_ws;

    float* Gp = (float*)ws;                                       // KS * 4 MB = 32 MB
    ushort_t* xhi = (ushort_t*)(ws + (size_t)32 * 1024 * 1024);   // 32 MB
    ushort_t* xlo = xhi + (size_t)NSAMP * D;                      // 32 MB
    float* sq = (float*)(ws + (size_t)96 * 1024 * 1024);          // 4 KB
    float* dsq = sq + NSAMP;                                      // 8 KB
    int* hp = (int*)(dsq + 2 * NSAMP);                            // 4 KB
    int* hn = hp + NSAMP;                                         // 4 KB

    k_norms_split<<<NSAMP, 256, 0, stream>>>(x, sq, xhi, xlo);
    k_gram_mfma<<<dim3(8, 8, KS), 256, 0, stream>>>(xhi, xlo, Gp);
    k_select<<<NSAMP, 256, 0, stream>>>(Gp, sq, tgt, hp, hn, dsq);
    k_dc_mfma<<<dim3(NSAMP, 2), 256, 0, stream>>>(xhi, hp, hn, dsq);
    k_loss<<<1, 256, 0, stream>>>(dsq, out);
}

// Round 4
// 248.332 us; speedup vs baseline: 3.5939x; 1.0779x over previous
//
#include <hip/hip_runtime.h>
#include <stdint.h>

#define NSAMP 1024
#define D 16384
#define WH 128
#define MARGIN 0.3f
#define KS 8
#define KSUB (D / KS)
#define SCALE 0.08838834764831845f    // 1/sqrt(128)
#define RSCALE 11.313708498984761f    // sqrt(128)

typedef unsigned int uint;
typedef unsigned short ushort_t;

typedef __attribute__((ext_vector_type(8))) short bf16x8;   // 8 bf16 = 4 VGPRs
typedef __attribute__((ext_vector_type(4))) float f32x4;

__device__ __forceinline__ float bf2f(unsigned short b) {
    return __uint_as_float(((uint)b) << 16);
}
__device__ __forceinline__ unsigned short f2bf(float f) {
    uint u = __float_as_uint(f);
    u += 0x7fffu + ((u >> 16) & 1u);   // RNE (data has no NaN)
    return (unsigned short)(u >> 16);
}
__device__ __forceinline__ void gload_lds16(const void* g, void* l) {
    __builtin_amdgcn_global_load_lds(
        (const __attribute__((address_space(1))) uint32_t*)g,
        (__attribute__((address_space(3))) uint32_t*)l, 16, 0, 0);
}
// Halve all 8 bf16 lanes: exponent-field decrement (exact for normal values;
// hi-split of N(0,1) data is never subnormal/zero, so no borrow is possible).
__device__ __forceinline__ bf16x8 bf8_half(bf16x8 v) {
    union { bf16x8 b; uint u[4]; } c;
    c.b = v;
    c.u[0] -= 0x00800080u; c.u[1] -= 0x00800080u;
    c.u[2] -= 0x00800080u; c.u[3] -= 0x00800080u;
    return c.b;
}
// Swizzled LDS byte offset for a 128-col bf16 row-major tile.
__device__ __forceinline__ int lds_off(int row, int col) {
    return row * 256 + ((((col >> 3) ^ (row & 15)) << 4) | ((col & 7) << 1));
}

// ---------------- kernel 1: row norms + hi/lo bf16 split ----------------
__global__ __launch_bounds__(256) void k_norms_split(const float* __restrict__ x,
                                                     float* __restrict__ sq,
                                                     ushort_t* __restrict__ xhi,
                                                     ushort_t* __restrict__ xlo) {
    int b = blockIdx.x;
    int tid = threadIdx.x;
    const float* xr = x + (size_t)b * D;
    ushort_t* hr = xhi + (size_t)b * D;
    ushort_t* lr = xlo + (size_t)b * D;
    float s = 0.f;
    #pragma unroll
    for (int m = 0; m < 16; ++m) {
        int e = m * 1024 + tid * 4;
        float4 v = *(const float4*)(xr + e);
        s += v.x * v.x + v.y * v.y + v.z * v.z + v.w * v.w;
        ushort4 h, l;
        h.x = f2bf(v.x); l.x = f2bf(v.x - bf2f(h.x));
        h.y = f2bf(v.y); l.y = f2bf(v.y - bf2f(h.y));
        h.z = f2bf(v.z); l.z = f2bf(v.z - bf2f(h.z));
        h.w = f2bf(v.w); l.w = f2bf(v.w - bf2f(h.w));
        *(ushort4*)(hr + e) = h;
        *(ushort4*)(lr + e) = l;
    }
    for (int off = 32; off; off >>= 1) s += __shfl_down(s, off, 64);
    __shared__ float red[4];
    if ((tid & 63) == 0) red[tid >> 6] = s;
    __syncthreads();
    if (tid == 0) sq[b] = red[0] + red[1] + red[2] + red[3];
}

// ---------------- kernel 2: GB = 0.5*Hi.Hi^T + Hi.Lo^T via MFMA ----------------
// G[i,j] is later recovered as sum_s GB_s[i,j] + GB_s[j,i]  (exact same 3 products).
__global__ __launch_bounds__(256) void k_gram_mfma(const ushort_t* __restrict__ xhi,
                                                   const ushort_t* __restrict__ xlo,
                                                   float* __restrict__ Gp) {
    int bj = blockIdx.x, bi = blockIdx.y, ks = blockIdx.z;
    int i0 = bi * 128, j0 = bj * 128;
    int tid = threadIdx.x;
    int w = tid >> 6, lane = tid & 63;
    int wm = w & 1, wn = w >> 1;
    int quad = lane >> 4, m16 = lane & 15;
    int srow = lane >> 2, sseg = lane & 3;

    __shared__ __align__(16) ushort_t Ahi_s[128 * 32];
    __shared__ __align__(16) ushort_t Bhi_s[128 * 32];
    __shared__ __align__(16) ushort_t Blo_s[128 * 32];

    f32x4 acc[4][4];
    #pragma unroll
    for (int ii = 0; ii < 4; ++ii)
        #pragma unroll
        for (int jj = 0; jj < 4; ++jj)
            acc[ii][jj] = (f32x4){0.f, 0.f, 0.f, 0.f};

    const size_t Abase = (size_t)i0 * D;
    const size_t Bbase = (size_t)j0 * D;

    for (int kb = 0; kb < KSUB / 32; ++kb) {
        int k0 = ks * KSUB + kb * 32;
        #pragma unroll
        for (int c = 0; c < 2; ++c) {
            int r = w * 32 + c * 16 + srow;
            size_t go = (size_t)r * D + k0 + sseg * 8;
            int lo = (w * 32 + c * 16) * 32;
            gload_lds16(xhi + Abase + go, &Ahi_s[lo]);
            gload_lds16(xhi + Bbase + go, &Bhi_s[lo]);
            gload_lds16(xlo + Bbase + go, &Blo_s[lo]);
        }
        __syncthreads();

        bf16x8 ah[4], bh[4], bl[4];
        #pragma unroll
        for (int ii = 0; ii < 4; ++ii) {
            int ar = wm * 64 + ii * 16 + m16;
            ah[ii] = *(const bf16x8*)&Ahi_s[ar * 32 + quad * 8];
        }
        #pragma unroll
        for (int jj = 0; jj < 4; ++jj) {
            int br = wn * 64 + jj * 16 + m16;
            bh[jj] = *(const bf16x8*)&Bhi_s[br * 32 + quad * 8];
            bl[jj] = *(const bf16x8*)&Blo_s[br * 32 + quad * 8];
        }
        #pragma unroll
        for (int ii = 0; ii < 4; ++ii) {
            bf16x8 ahh = bf8_half(ah[ii]);
            #pragma unroll
            for (int jj = 0; jj < 4; ++jj) {
                acc[ii][jj] = __builtin_amdgcn_mfma_f32_16x16x32_bf16(ahh, bh[jj], acc[ii][jj], 0, 0, 0);
                acc[ii][jj] = __builtin_amdgcn_mfma_f32_16x16x32_bf16(ah[ii], bl[jj], acc[ii][jj], 0, 0, 0);
            }
        }
        __syncthreads();
    }

    float* Gb = Gp + (size_t)ks * NSAMP * NSAMP;
    #pragma unroll
    for (int ii = 0; ii < 4; ++ii)
        #pragma unroll
        for (int jj = 0; jj < 4; ++jj) {
            int rg = i0 + wm * 64 + ii * 16 + quad * 4;
            int cg = j0 + wn * 64 + jj * 16 + m16;
            #pragma unroll
            for (int r = 0; r < 4; ++r)
                Gb[(size_t)(rg + r) * NSAMP + cg] = acc[ii][jj][r];
        }
}

// ---------------- kernel 2b: fold the KS partials -> Gsum ----------------
__global__ __launch_bounds__(256) void k_fold(const float* __restrict__ Gp,
                                              float* __restrict__ Gsum) {
    size_t idx = ((size_t)blockIdx.x * 256 + threadIdx.x) * 4;
    float4 s = *(const float4*)(Gp + idx);
    #pragma unroll
    for (int p = 1; p < KS; ++p) {
        float4 v = *(const float4*)(Gp + (size_t)p * NSAMP * NSAMP + idx);
        s.x += v.x; s.y += v.y; s.z += v.z; s.w += v.w;
    }
    *(float4*)(Gsum + idx) = s;
}

// ---------------- kernel 3: hardest pos/neg + dsq init ----------------
// G[i,j] = Gsum[i,j] + Gsum[j,i]
__global__ void k_select(const float* __restrict__ Gsum,
                         const float* __restrict__ sq, const int* __restrict__ tgt,
                         int* __restrict__ hp, int* __restrict__ hn,
                         float* __restrict__ dsq) {
    int i = blockIdx.x;
    int tid = threadIdx.x;
    float sqi = sq[i];
    int ti = tgt[i];
    float pv = -3.0e38f; int pj = 0x7FFFFFFF;
    float nv = 3.0e38f;  int nj = 0x7FFFFFFF;
    #pragma unroll
    for (int m = 0; m < 4; ++m) {
        int j = tid + 256 * m;
        float g = Gsum[(size_t)i * NSAMP + j] + Gsum[(size_t)j * NSAMP + i];
        float d2 = sqi + sq[j] - 2.f * g;
        float d = sqrtf(fmaxf(d2, 1e-12f));
        bool same = (tgt[j] == ti);
        float cp = same ? d : -1e30f;
        float cn = same ? 1e30f : d;
        if (cp > pv || (cp == pv && j < pj)) { pv = cp; pj = j; }
        if (cn < nv || (cn == nv && j < nj)) { nv = cn; nj = j; }
    }
    for (int off = 32; off; off >>= 1) {
        float opv = __shfl_down(pv, off, 64); int opj = __shfl_down(pj, off, 64);
        float onv = __shfl_down(nv, off, 64); int onj = __shfl_down(nj, off, 64);
        if (opv > pv || (opv == pv && opj < pj)) { pv = opv; pj = opj; }
        if (onv < nv || (onv == nv && onj < nj)) { nv = onv; nj = onj; }
    }
    __shared__ float spv[4], snv[4];
    __shared__ int spj[4], snj[4];
    if ((tid & 63) == 0) { int wv = tid >> 6; spv[wv] = pv; spj[wv] = pj; snv[wv] = nv; snj[wv] = nj; }
    __syncthreads();
    if (tid == 0) {
        for (int wv = 1; wv < 4; ++wv) {
            if (spv[wv] > pv || (spv[wv] == pv && spj[wv] < pj)) { pv = spv[wv]; pj = spj[wv]; }
            if (snv[wv] < nv || (snv[wv] == nv && snj[wv] < nj)) { nv = snv[wv]; nj = snj[wv]; }
        }
        hp[i] = pj; hn[i] = nj;
        // dsq = ||A||^2 init; k_dc adds (-2*Tr(A.M) + ||M||^2)
        dsq[i] = sqi; dsq[NSAMP + i] = sqi;
    }
}

// ---------------- kernel 4: DC align via MFMA (flash-style) ----------------
__global__ __launch_bounds__(256) void k_dc_mfma(const ushort_t* __restrict__ xhi,
                                                 const int* __restrict__ hp,
                                                 const int* __restrict__ hn,
                                                 float* __restrict__ dsq) {
    int b = blockIdx.x;
    int which = blockIdx.y;
    int oidx = (which == 0) ? hp[b] : hn[b];
    const ushort_t* Ag = xhi + (size_t)b * D;
    const ushort_t* Og = xhi + (size_t)oidx * D;

    __shared__ __align__(16) char smem[65536];   // [0,32K): O then Ot; [32K,64K): P

    int tid = threadIdx.x;
    int wv = tid >> 6, lane = tid & 63;
    int quad = lane >> 4, m16 = lane & 15;

    bf16x8 af[2][4];
    #pragma unroll
    for (int tj2 = 0; tj2 < 2; ++tj2) {
        int r = (2 * wv + tj2) * 16 + m16;
        #pragma unroll
        for (int ks = 0; ks < 4; ++ks)
            af[tj2][ks] = *(const bf16x8*)(Ag + r * WH + ks * 32 + quad * 8);
    }

    uint4 stg[8];
    #pragma unroll
    for (int k = 0; k < 8; ++k)
        stg[k] = *(const uint4*)((const char*)Og + (size_t)(tid + 256 * k) * 16);
    #pragma unroll
    for (int k = 0; k < 8; ++k) {
        int g = tid + 256 * k;
        *(uint4*)(smem + lds_off(g >> 4, (g & 15) * 8)) = stg[k];
    }
    __syncthreads();

    // ---- S^T pass ----
    f32x4 accS[8][2];
    #pragma unroll
    for (int ti = 0; ti < 8; ++ti)
        #pragma unroll
        for (int tj2 = 0; tj2 < 2; ++tj2)
            accS[ti][tj2] = (f32x4){0.f, 0.f, 0.f, 0.f};
    #pragma unroll
    for (int ks = 0; ks < 4; ++ks) {
        bf16x8 of[8];
        #pragma unroll
        for (int ti = 0; ti < 8; ++ti)
            of[ti] = *(const bf16x8*)(smem + lds_off(ti * 16 + m16, (ks * 4 + quad) * 8));
        #pragma unroll
        for (int ti = 0; ti < 8; ++ti)
            #pragma unroll
            for (int tj2 = 0; tj2 < 2; ++tj2)
                accS[ti][tj2] = __builtin_amdgcn_mfma_f32_16x16x32_bf16(of[ti], af[tj2][ks], accS[ti][tj2], 0, 0, 0);
    }

    int c0 = (tid & 31) * 4, h0 = (tid >> 5) * 16;
    uint4 trd[4][2];
    #pragma unroll
    for (int j = 0; j < 4; ++j)
        #pragma unroll
        for (int k = 0; k < 2; ++k)
            trd[j][k] = *(const uint4*)(smem + lds_off(c0 + j, h0 + 8 * k));

    // ---- softmax over c, write normalized bf16 P, T partial ----
    float tpart = 0.f;
    #pragma unroll
    for (int tj2 = 0; tj2 < 2; ++tj2) {
        float mx = -3.0e38f;
        #pragma unroll
        for (int ti = 0; ti < 8; ++ti)
            #pragma unroll
            for (int r = 0; r < 4; ++r) {
                float s = accS[ti][tj2][r] * SCALE;
                accS[ti][tj2][r] = s;
                mx = fmaxf(mx, s);
            }
        mx = fmaxf(mx, __shfl_xor(mx, 16, 64));
        mx = fmaxf(mx, __shfl_xor(mx, 32, 64));
        float sum = 0.f;
        #pragma unroll
        for (int ti = 0; ti < 8; ++ti)
            #pragma unroll
            for (int r = 0; r < 4; ++r)
                sum += __expf(accS[ti][tj2][r] - mx);
        sum += __shfl_xor(sum, 16, 64);
        sum += __shfl_xor(sum, 32, 64);
        float inv = 1.f / sum;
        int rrow = (2 * wv + tj2) * 16 + m16;
        #pragma unroll
        for (int ti = 0; ti < 8; ++ti) {
            uint pk0 = 0, pk1 = 0;
            #pragma unroll
            for (int r = 0; r < 4; ++r) {
                float s = accS[ti][tj2][r];
                float p = __expf(s - mx) * inv;
                unsigned short pb = f2bf(p);
                tpart += s * bf2f(pb);
                uint pu = (uint)pb << ((r & 1) * 16);
                if (r < 2) pk0 |= pu; else pk1 |= pu;
            }
            *(uint2*)(smem + 32768 + lds_off(rrow, ti * 16 + quad * 4)) = make_uint2(pk0, pk1);
        }
    }
    __syncthreads();

    // ---- transpose write: (c,h) -> (h,c) ----
    #pragma unroll
    for (int i = 0; i < 16; ++i) {
        uint v[4];
        #pragma unroll
        for (int j = 0; j < 4; ++j) {
            uint wo = ((const uint*)&trd[j][i >> 3])[(i >> 1) & 3];
            v[j] = (i & 1) ? (wo >> 16) : (wo & 0xffffu);
        }
        uint2 pk;
        pk.x = v[0] | (v[1] << 16);
        pk.y = v[2] | (v[3] << 16);
        *(uint2*)(smem + lds_off(h0 + i, c0)) = pk;
    }
    __syncthreads();

    // ---- M pass ----
    f32x4 accM[2][8];
    #pragma unroll
    for (int tj2 = 0; tj2 < 2; ++tj2)
        #pragma unroll
        for (int tj = 0; tj < 8; ++tj)
            accM[tj2][tj] = (f32x4){0.f, 0.f, 0.f, 0.f};
    #pragma unroll
    for (int ks = 0; ks < 4; ++ks) {
        bf16x8 pfr[2], otf[8];
        #pragma unroll
        for (int tj2 = 0; tj2 < 2; ++tj2)
            pfr[tj2] = *(const bf16x8*)(smem + 32768 + lds_off((2 * wv + tj2) * 16 + m16, (ks * 4 + quad) * 8));
        #pragma unroll
        for (int tj = 0; tj < 8; ++tj)
            otf[tj] = *(const bf16x8*)(smem + lds_off(tj * 16 + m16, (ks * 4 + quad) * 8));
        #pragma unroll
        for (int tj2 = 0; tj2 < 2; ++tj2)
            #pragma unroll
            for (int tj = 0; tj < 8; ++tj)
                accM[tj2][tj] = __builtin_amdgcn_mfma_f32_16x16x32_bf16(pfr[tj2], otf[tj], accM[tj2][tj], 0, 0, 0);
    }

    float m2 = 0.f;
    #pragma unroll
    for (int tj2 = 0; tj2 < 2; ++tj2)
        #pragma unroll
        for (int tj = 0; tj < 8; ++tj)
            #pragma unroll
            for (int r = 0; r < 4; ++r) {
                float mvv = accM[tj2][tj][r];
                m2 += mvv * mvv;
            }
    float part = m2 - 2.f * RSCALE * tpart;
    for (int off = 32; off; off >>= 1) part += __shfl_down(part, off, 64);
    if (lane == 0) atomicAdd(&dsq[which * NSAMP + b], part);
}

// ---------------- kernel 5: final loss ----------------
__global__ void k_loss(const float* __restrict__ dsq, float* __restrict__ out) {
    int tid = threadIdx.x;
    float s = 0.f;
    #pragma unroll
    for (int m = 0; m < 4; ++m) {
        int b = tid + 256 * m;
        float ap = sqrtf(fmaxf(dsq[b], 0.f));
        float an = sqrtf(fmaxf(dsq[NSAMP + b], 0.f));
        s += fmaxf(ap - an + MARGIN, 0.f);
    }
    for (int off = 32; off; off >>= 1) s += __shfl_down(s, off, 64);
    __shared__ float red[4];
    if ((tid & 63) == 0) red[tid >> 6] = s;
    __syncthreads();
    if (tid == 0) out[0] = (red[0] + red[1] + red[2] + red[3]) * (1.f / NSAMP);
}

extern "C" void kernel_launch(void* const* d_in, const int* in_sizes, int n_in,
                              void* d_out, int out_size, void* d_ws, size_t ws_size,
                              hipStream_t stream) {
    const float* x = (const float*)d_in[0];
    const int* tgt = (const int*)d_in[1];
    float* out = (float*)d_out;
    char* ws = (char*)d_ws;

    float* Gp = (float*)ws;                                       // KS * 4 MB = 32 MB
    ushort_t* xhi = (ushort_t*)(ws + (size_t)32 * 1024 * 1024);   // 32 MB
    ushort_t* xlo = xhi + (size_t)NSAMP * D;                      // 32 MB (dead after gram)
    float* Gsum = (float*)xlo;                                    // 4 MB, overlaps xlo
    float* sq = (float*)(ws + (size_t)96 * 1024 * 1024);          // 4 KB
    float* dsq = sq + NSAMP;                                      // 8 KB
    int* hp = (int*)(dsq + 2 * NSAMP);                            // 4 KB
    int* hn = hp + NSAMP;                                         // 4 KB

    k_norms_split<<<NSAMP, 256, 0, stream>>>(x, sq, xhi, xlo);
    k_gram_mfma<<<dim3(8, 8, KS), 256, 0, stream>>>(xhi, xlo, Gp);
    k_fold<<<NSAMP, 256, 0, stream>>>(Gp, Gsum);
    k_select<<<NSAMP, 256, 0, stream>>>(Gsum, sq, tgt, hp, hn, dsq);
    k_dc_mfma<<<dim3(NSAMP, 2), 256, 0, stream>>>(xhi, hp, hn, dsq);
    k_loss<<<1, 256, 0, stream>>>(dsq, out);
}